// Round 1
// baseline (2682.439 us; speedup 1.0000x reference)
//
#include <hip/hip_runtime.h>
#include <math.h>

#define BB 256
#define WW 128
#define LL 3
#define ND 172
#define EVK 347   // ED(172) + 3 + ND(172)
#define HH 128
#define D2 256
#define MD 140
#define NTH 256

// ---------------- kernel 1: global std over diff = |cut - time_idx[:,:,:2]| ----------------
__global__ __launch_bounds__(NTH) void k_std(const float* __restrict__ time_idx,
                                             const float* __restrict__ cut,
                                             double* __restrict__ acc) {
    int tid = threadIdx.x;
    const int n = BB * WW * 2;
    double s = 0.0, s2 = 0.0;
    for (int i = blockIdx.x * blockDim.x + tid; i < n; i += gridDim.x * blockDim.x) {
        int j  = i & 1;
        int bw = i >> 1;
        int b  = bw / WW;
        float d = fabsf(cut[b] - time_idx[bw * LL + j]);
        s  += (double)d;
        s2 += (double)d * (double)d;
    }
    __shared__ double ls[NTH], ls2[NTH];
    ls[tid] = s; ls2[tid] = s2;
    __syncthreads();
    for (int st = NTH / 2; st > 0; st >>= 1) {
        if (tid < st) { ls[tid] += ls[tid + st]; ls2[tid] += ls2[tid + st]; }
        __syncthreads();
    }
    if (tid == 0) {
        atomicAdd(&acc[0], ls[0]);
        atomicAdd(&acc[1], ls2[0]);
    }
}

// ---------------- kernel 2: fully fused per-(b,w) pipeline ----------------
__global__ __launch_bounds__(NTH) void k_main(
    const float* __restrict__ node_table, const float* __restrict__ edge_table,
    const float* __restrict__ basis_freq, const float* __restrict__ phase,
    const float* __restrict__ ev_W,   const float* __restrict__ ev_b,
    const float* __restrict__ ev_m1W, const float* __restrict__ ev_m1b,
    const float* __restrict__ ev_m2W, const float* __restrict__ ev_m2b,
    const float* __restrict__ at_W1,  const float* __restrict__ at_b1,
    const float* __restrict__ at_W2,  const float* __restrict__ at_b2,
    const float* __restrict__ at_m1W, const float* __restrict__ at_m1b,
    const float* __restrict__ at_m2W, const float* __restrict__ at_m2b,
    const float* __restrict__ f_W1,   const float* __restrict__ f_b1,
    const float* __restrict__ f_W2,   const float* __restrict__ f_b2,
    const float* __restrict__ f_W3,   const float* __restrict__ f_b3,
    const float* __restrict__ time_idx, const float* __restrict__ cut_time_l,
    const float* __restrict__ cat_feat, const float* __restrict__ edge_identify,
    const int* __restrict__ node_idx,   const int* __restrict__ edge_idx,
    const double* __restrict__ acc, float* __restrict__ out)
{
    const int bw  = blockIdx.x;
    const int b   = bw / WW;
    const int tid = threadIdx.x;

    __shared__ float evt[LL][EVK + 1];  // event vector: [edge_feat | edge_id | time_feat]
    __shared__ float sf[LL][ND];        // src node feats
    __shared__ float tf[LL][ND];        // tgt node feats
    __shared__ float ev[LL][ND];        // event @ ev_W + ev_b (shared by both conv dirs)
    __shared__ float am[LL][ND];        // s + relu(t + ev)
    __shared__ float hh[LL][HH];
    __shared__ float upd[LL][D2];
    __shared__ float wp[D2];
    __shared__ float wq[2][D2];
    __shared__ float outf[D2];
    __shared__ float h2[HH];
    __shared__ float h3[HH];
    __shared__ float xz[MD];
    __shared__ float z1[MD];
    __shared__ float z2[HH];
    __shared__ float red[NTH];
    __shared__ float sc[2];

    const float cut = cut_time_l[b];

    // ---- stage 0: gather edge/node rows, compute time features ----
    for (int i = tid; i < LL * ND; i += NTH) {
        int l = i / ND, k = i % ND;
        int eidx = edge_idx[bw * LL + l];
        evt[l][k] = edge_table[(long)eidx * ND + k];
        float delta = cut - time_idx[bw * LL + l];
        evt[l][ND + 3 + k] = cosf(delta * basis_freq[k] + phase[k]);
        int sidx = node_idx[bw * 2 * LL + 2 * l];
        int tidx = node_idx[bw * 2 * LL + 2 * l + 1];
        sf[l][k] = node_table[(long)sidx * ND + k];
        tf[l][k] = node_table[(long)tidx * ND + k];
    }
    if (tid < LL * 3) {
        int l = tid / 3, j = tid % 3;
        evt[l][ND + j] = edge_identify[(bw * LL + l) * 3 + j];
    }
    __syncthreads();

    // ---- stage 1: ev = event @ ev_W + ev_b  (3 x 172) ----
    for (int i = tid; i < LL * ND; i += NTH) {
        int l = i / ND, d = i % ND;
        float a = ev_b[d];
        for (int k = 0; k < EVK; ++k)
            a = fmaf(evt[l][k], ev_W[k * ND + d], a);
        ev[l][d] = a;
    }
    __syncthreads();

    // ---- stage 2: two conv directions ----
    for (int dir = 0; dir < 2; ++dir) {
        const float (*S)[ND] = (dir == 0) ? sf : tf;
        const float (*T)[ND] = (dir == 0) ? tf : sf;
        for (int i = tid; i < LL * ND; i += NTH) {
            int l = i / ND, d = i % ND;
            float msg = T[l][d] + ev[l][d];
            msg = msg > 0.f ? msg : 0.f;
            am[l][d] = S[l][d] + msg;
        }
        __syncthreads();
        for (int i = tid; i < LL * HH; i += NTH) {
            int l = i / HH, j = i % HH;
            float a = ev_m1b[j];
            for (int d = 0; d < ND; ++d)
                a = fmaf(am[l][d], ev_m1W[d * HH + j], a);
            hh[l][j] = a > 0.f ? a : 0.f;
        }
        __syncthreads();
        for (int i = tid; i < LL * HH; i += NTH) {
            int l = i / HH, j = i % HH;
            float a = ev_m2b[j];
            for (int d = 0; d < HH; ++d)
                a = fmaf(hh[l][d], ev_m2W[d * HH + j], a);
            upd[l][dir * HH + j] = a;
        }
        __syncthreads();
    }

    // ---- stage 3: attention projections (Wp from upd[2], Wq[j] from upd[j]) ----
    {
        int d = tid;  // D2 == NTH
        float a = at_b1[d];
        for (int k = 0; k < D2; ++k)
            a = fmaf(upd[2][k], at_W1[k * D2 + d], a);
        wp[d] = a;
        float q0 = at_b2[d], q1 = at_b2[d];
        for (int k = 0; k < D2; ++k) {
            float wv = at_W2[k * D2 + d];
            q0 = fmaf(upd[0][k], wv, q0);
            q1 = fmaf(upd[1][k], wv, q1);
        }
        wq[0][d] = q0; wq[1][d] = q1;
    }
    __syncthreads();

    // ---- stage 4: scores = Wp . Wq[j] ----
    for (int j = 0; j < 2; ++j) {
        red[tid] = wp[tid] * wq[j][tid];
        __syncthreads();
        for (int st = NTH / 2; st > 0; st >>= 1) {
            if (tid < st) red[tid] += red[tid + st];
            __syncthreads();
        }
        if (tid == 0) sc[j] = red[0];
        __syncthreads();
    }

    // ---- stage 5: time weighting + softmax + attention output ----
    {
        const double n = (double)(BB * WW * 2);
        float stdv = (float)sqrt((acc[1] - acc[0] * acc[0] / n) / (n - 1.0));
        float d0 = fabsf(cut - time_idx[bw * LL + 0]);
        float d1 = fabsf(cut - time_idx[bw * LL + 1]);
        float tw0 = expf(-d0 / (stdv + 1e-6f));
        float tw1 = expf(-d1 / (stdv + 1e-6f));
        float s0 = sc[0] * (0.7f + 0.3f * tw0);
        float s1 = sc[1] * (0.7f + 0.3f * tw1);
        float m  = fmaxf(s0, s1);
        float e0 = expf(s0 - m), e1 = expf(s1 - m);
        float inv = 1.f / (e0 + e1);
        float a0 = e0 * inv, a1 = e1 * inv;
        outf[tid] = upd[2][tid] + a0 * wq[0][tid] + a1 * wq[1][tid];
    }
    __syncthreads();

    // ---- stage 6: attention MLP head ----
    if (tid < HH) {
        float a = at_m1b[tid];
        for (int d = 0; d < D2; ++d)
            a = fmaf(outf[d], at_m1W[d * HH + tid], a);
        h2[tid] = a > 0.f ? a : 0.f;
    }
    __syncthreads();
    if (tid < HH) {
        float a = at_m2b[tid];
        for (int d = 0; d < HH; ++d)
            a = fmaf(h2[d], at_m2W[d * HH + tid], a);
        h3[tid] = a;
    }
    __syncthreads();
    if (tid < MD) xz[tid] = (tid < HH) ? h3[tid] : cat_feat[bw * 12 + (tid - HH)];
    __syncthreads();

    // ---- stage 7: final MLP ----
    if (tid < MD) {
        float a = f_b1[tid];
        for (int k = 0; k < MD; ++k)
            a = fmaf(xz[k], f_W1[k * MD + tid], a);
        z1[tid] = a > 0.f ? a : 0.f;
    }
    __syncthreads();
    if (tid < HH) {
        float a = f_b2[tid];
        for (int k = 0; k < MD; ++k)
            a = fmaf(z1[k], f_W2[k * HH + tid], a);
        z2[tid] = a > 0.f ? a : 0.f;
    }
    __syncthreads();
    red[tid] = (tid < HH) ? z2[tid] * f_W3[tid] : 0.f;
    __syncthreads();
    for (int st = NTH / 2; st > 0; st >>= 1) {
        if (tid < st) red[tid] += red[tid + st];
        __syncthreads();
    }
    if (tid == 0) out[bw] = red[0] + f_b3[0];
}

extern "C" void kernel_launch(void* const* d_in, const int* in_sizes, int n_in,
                              void* d_out, int out_size, void* d_ws, size_t ws_size,
                              hipStream_t stream) {
    const float* node_table    = (const float*)d_in[0];
    const float* edge_table    = (const float*)d_in[1];
    const float* basis_freq    = (const float*)d_in[2];
    const float* phase         = (const float*)d_in[3];
    const float* ev_W          = (const float*)d_in[4];
    const float* ev_b          = (const float*)d_in[5];
    const float* ev_m1W        = (const float*)d_in[6];
    const float* ev_m1b        = (const float*)d_in[7];
    const float* ev_m2W        = (const float*)d_in[8];
    const float* ev_m2b        = (const float*)d_in[9];
    const float* at_W1         = (const float*)d_in[10];
    const float* at_b1         = (const float*)d_in[11];
    const float* at_W2         = (const float*)d_in[12];
    const float* at_b2         = (const float*)d_in[13];
    const float* at_m1W        = (const float*)d_in[14];
    const float* at_m1b        = (const float*)d_in[15];
    const float* at_m2W        = (const float*)d_in[16];
    const float* at_m2b        = (const float*)d_in[17];
    const float* f_W1          = (const float*)d_in[18];
    const float* f_b1          = (const float*)d_in[19];
    const float* f_W2          = (const float*)d_in[20];
    const float* f_b2          = (const float*)d_in[21];
    const float* f_W3          = (const float*)d_in[22];
    const float* f_b3          = (const float*)d_in[23];
    const float* time_idx      = (const float*)d_in[24];
    const float* cut_time_l    = (const float*)d_in[25];
    const float* cat_feat      = (const float*)d_in[26];
    const float* edge_identify = (const float*)d_in[27];
    const int*   node_idx      = (const int*)d_in[28];
    const int*   edge_idx      = (const int*)d_in[29];

    double* acc = (double*)d_ws;
    hipMemsetAsync(d_ws, 0, 2 * sizeof(double), stream);
    k_std<<<64, NTH, 0, stream>>>(time_idx, cut_time_l, acc);
    k_main<<<BB * WW, NTH, 0, stream>>>(
        node_table, edge_table, basis_freq, phase, ev_W, ev_b,
        ev_m1W, ev_m1b, ev_m2W, ev_m2b, at_W1, at_b1, at_W2, at_b2,
        at_m1W, at_m1b, at_m2W, at_m2b, f_W1, f_b1, f_W2, f_b2, f_W3, f_b3,
        time_idx, cut_time_l, cat_feat, edge_identify, node_idx, edge_idx,
        acc, (float*)d_out);
}

// Round 2
// 1154.884 us; speedup vs baseline: 2.3227x; 2.3227x over previous
//
#include <hip/hip_runtime.h>
#include <math.h>

#define NWIN_TOTAL (256 * 128)
#define LL 3
#define NDIM 172
#define NTH 256

#define CDIV(a, b) (((a) + (b) - 1) / (b))

// per-window workspace bytes (3 aliased regions)
#define R1_PW 4176   // evt[3][348] f32; later h1[3][128], then wp[256]+wq[2][256]
#define R2_PW 2064   // ev[3][172]; later outf[256]+h2[128]
#define R3_PW 3072   // upd[3][256]; later xz[144]+z1[144]+z2[128]
#define PW_BYTES (R1_PW + R2_PW + R3_PW)

// ---------------- global std over diff = |cut - time_idx[:,:,:2]| ----------------
__global__ __launch_bounds__(NTH) void k_std(const float* __restrict__ time_idx,
                                             const float* __restrict__ cut,
                                             double* __restrict__ acc) {
    int tid = threadIdx.x;
    const int n = NWIN_TOTAL * 2;
    double s = 0.0, s2 = 0.0;
    for (int i = blockIdx.x * blockDim.x + tid; i < n; i += gridDim.x * blockDim.x) {
        int j = i & 1;
        int bw = i >> 1;
        float d = fabsf(cut[bw >> 7] - time_idx[bw * LL + j]);
        s += (double)d;
        s2 += (double)d * (double)d;
    }
    __shared__ double ls[NTH], ls2[NTH];
    ls[tid] = s; ls2[tid] = s2;
    __syncthreads();
    for (int st = NTH / 2; st > 0; st >>= 1) {
        if (tid < st) { ls[tid] += ls[tid + st]; ls2[tid] += ls2[tid + st]; }
        __syncthreads();
    }
    if (tid == 0) { atomicAdd(&acc[0], ls[0]); atomicAdd(&acc[1], ls[1] * 0.0 + ls2[0]); }
}

// ---------------- evt builder: [edge(172) | id(3) | 0 | time(172)] = 348 cols ----------------
__global__ __launch_bounds__(NTH) void k_evt(
    const float* __restrict__ edge_table, const float* __restrict__ basis_freq,
    const float* __restrict__ phase, const float* __restrict__ time_idx,
    const float* __restrict__ cut, const float* __restrict__ edge_identify,
    const int* __restrict__ edge_idx, float* __restrict__ evt,
    int Mrows, int win0) {
    for (int rr = 0; rr < 8; ++rr) {
        int row = blockIdx.x * 8 + rr;
        if (row >= Mrows) return;
        int w = row / 3, l = row - 3 * w;
        int gw = win0 + w;
        int eidx = edge_idx[gw * 3 + l];
        float delta = cut[gw >> 7] - time_idx[gw * 3 + l];
        float* dst = evt + (size_t)row * 348;
        const float* er = edge_table + (size_t)eidx * NDIM;
        for (int p = threadIdx.x; p < 348; p += NTH) {
            float v;
            if (p < 172) v = er[p];
            else if (p < 175) v = edge_identify[(gw * 3 + l) * 3 + (p - 172)];
            else if (p == 175) v = 0.f;
            else { int k = p - 176; v = cosf(fmaf(delta, basis_freq[k], phase[k])); }
            dst[p] = v;
        }
    }
}

// ---------------- generic register-tiled GEMM core ----------------
// At: LDS A-tile [32][KAPAD].  C[grow][col] = act(sum_k At[r][k]*W[wmap(k)][col] + bias[col])
// thread map: c = tid&31 (cols c+32j, j<DT), r0 = (tid>>5)*4 (4 rows)
template <int KAPAD, int KW, int NW, int DT, int WSKIP, int ACT>
__device__ __forceinline__ void gemm_core(const float* At,
                                          const float* __restrict__ W,
                                          const float* __restrict__ bias,
                                          float* __restrict__ Cout,
                                          int M, int ostride, int ocol0) {
    const int c = threadIdx.x & 31;
    const int r0 = (threadIdx.x >> 5) << 2;
    float acc[4][DT];
#pragma unroll
    for (int r = 0; r < 4; ++r)
#pragma unroll
        for (int j = 0; j < DT; ++j) acc[r][j] = 0.f;

    constexpr int NC = KAPAD / 4;
#pragma unroll 1
    for (int kc = 0; kc < NC; ++kc) {
        const int p0 = kc * 4;
        const int wr = WSKIP ? (p0 >= 176 ? p0 - 1 : p0) : p0;
        float a[4][4];
#pragma unroll
        for (int r = 0; r < 4; ++r) {
            float4 v = *(const float4*)&At[(r0 + r) * KAPAD + p0];
            a[r][0] = v.x; a[r][1] = v.y; a[r][2] = v.z; a[r][3] = v.w;
        }
#pragma unroll
        for (int i = 0; i < 4; ++i) {
            const int kr = wr + i;
            float wv[DT];
#pragma unroll
            for (int j = 0; j < DT; ++j) {
                const int col = c + 32 * j;
                bool ok = true;
                if (KW < KAPAD || WSKIP) ok = (kr < KW);
                if (NW % 32) ok = ok && (col < NW);
                wv[j] = ok ? W[(size_t)kr * NW + col] : 0.f;
            }
#pragma unroll
            for (int j = 0; j < DT; ++j) {
                acc[0][j] = fmaf(a[0][i], wv[j], acc[0][j]);
                acc[1][j] = fmaf(a[1][i], wv[j], acc[1][j]);
                acc[2][j] = fmaf(a[2][i], wv[j], acc[2][j]);
                acc[3][j] = fmaf(a[3][i], wv[j], acc[3][j]);
            }
        }
    }
    const int growb = blockIdx.x * 32;
#pragma unroll
    for (int r = 0; r < 4; ++r) {
        int grow = growb + r0 + r;
        if (grow < M) {
#pragma unroll
            for (int j = 0; j < DT; ++j) {
                int col = c + 32 * j;
                if (!(NW % 32) || col < NW) {
                    float v = acc[r][j] + bias[col];
                    if (ACT) v = v > 0.f ? v : 0.f;
                    Cout[(size_t)grow * ostride + ocol0 + col] = v;
                }
            }
        }
    }
}

// remap: 0 = identity, 1 = wp rows (w*3+2), 2 = wq rows ((w>>1)*3 + (w&1))
template <int KAPAD, int KW, int NW, int DT, int WSKIP, int ACT>
__global__ __launch_bounds__(NTH) void k_gemm(const float* __restrict__ A,
                                              const float* __restrict__ W,
                                              const float* __restrict__ bias,
                                              float* __restrict__ Cout,
                                              int M, int ostride, int ocol0, int remap) {
    __shared__ float At[32 * KAPAD];
    constexpr int NQ = KAPAD / 4;
    for (int i = threadIdx.x; i < 32 * NQ; i += NTH) {
        int r = i / NQ, q = i - r * NQ;
        int grow = blockIdx.x * 32 + r;
        if (grow >= M) grow = M - 1;
        int arow = (remap == 0) ? grow : ((remap == 1) ? grow * 3 + 2 : (grow >> 1) * 3 + (grow & 1));
        *(float4*)&At[r * KAPAD + 4 * q] = *(const float4*)&A[(size_t)arow * KAPAD + 4 * q];
    }
    __syncthreads();
    gemm_core<KAPAD, KW, NW, DT, WSKIP, ACT>(At, W, bias, Cout, M, ostride, ocol0);
}

// conv stage 2a: build am = S + relu(T + ev) into the A-tile, then GEMM with ev_m1W
__global__ __launch_bounds__(NTH) void k_gemm_am(const float* __restrict__ ev,
                                                 const float* __restrict__ node_table,
                                                 const int* __restrict__ node_idx,
                                                 const float* __restrict__ W,
                                                 const float* __restrict__ bias,
                                                 float* __restrict__ h1,
                                                 int M, int win0, int dir) {
    __shared__ float At[32 * 172];
    for (int i = threadIdx.x; i < 32 * 43; i += NTH) {
        int r = i / 43, q = i - r * 43;
        int grow = blockIdx.x * 32 + r;
        if (grow >= M) grow = M - 1;
        int w = grow / 3, l = grow - 3 * w;
        int gw = win0 + w;
        int si = node_idx[gw * 6 + 2 * l + (dir ? 1 : 0)];
        int ti = node_idx[gw * 6 + 2 * l + (dir ? 0 : 1)];
        float4 s4 = *(const float4*)&node_table[(size_t)si * NDIM + 4 * q];
        float4 t4 = *(const float4*)&node_table[(size_t)ti * NDIM + 4 * q];
        float4 e4 = *(const float4*)&ev[(size_t)grow * NDIM + 4 * q];
        float4 o;
        o.x = s4.x + fmaxf(t4.x + e4.x, 0.f);
        o.y = s4.y + fmaxf(t4.y + e4.y, 0.f);
        o.z = s4.z + fmaxf(t4.z + e4.z, 0.f);
        o.w = s4.w + fmaxf(t4.w + e4.w, 0.f);
        *(float4*)&At[r * 172 + 4 * q] = o;
    }
    __syncthreads();
    gemm_core<172, 172, 128, 4, 0, 1>(At, W, bias, h1, M, 128, 0);
}

// attention combine: scores, time weighting, softmax, outf = upd[2] + a0*wq0 + a1*wq1
__global__ __launch_bounds__(NTH) void k_comb(const float* __restrict__ wp,
                                              const float* __restrict__ wq,
                                              const float* __restrict__ upd,
                                              const float* __restrict__ time_idx,
                                              const float* __restrict__ cut,
                                              const double* __restrict__ acc,
                                              float* __restrict__ outf, int win0) {
    const int w = blockIdx.x, t = threadIdx.x;
    const int gw = win0 + w;
    __shared__ float red[NTH];
    __shared__ float sc[2];
    float wpv = wp[(size_t)w * 256 + t];
    float q0 = wq[(size_t)(w * 2 + 0) * 256 + t];
    float q1 = wq[(size_t)(w * 2 + 1) * 256 + t];
    red[t] = wpv * q0;
    __syncthreads();
    for (int st = NTH / 2; st > 0; st >>= 1) { if (t < st) red[t] += red[t + st]; __syncthreads(); }
    if (t == 0) sc[0] = red[0];
    __syncthreads();
    red[t] = wpv * q1;
    __syncthreads();
    for (int st = NTH / 2; st > 0; st >>= 1) { if (t < st) red[t] += red[t + st]; __syncthreads(); }
    if (t == 0) sc[1] = red[0];
    __syncthreads();

    const double n = (double)(NWIN_TOTAL * 2);
    float stdv = (float)sqrt((acc[1] - acc[0] * acc[0] / n) / (n - 1.0));
    float cutv = cut[gw >> 7];
    float d0 = fabsf(cutv - time_idx[gw * 3 + 0]);
    float d1 = fabsf(cutv - time_idx[gw * 3 + 1]);
    float tw0 = expf(-d0 / (stdv + 1e-6f));
    float tw1 = expf(-d1 / (stdv + 1e-6f));
    float s0 = sc[0] * (0.7f + 0.3f * tw0);
    float s1 = sc[1] * (0.7f + 0.3f * tw1);
    float m = fmaxf(s0, s1);
    float e0 = expf(s0 - m), e1 = expf(s1 - m);
    float inv = 1.f / (e0 + e1);
    float a0 = e0 * inv, a1 = e1 * inv;
    outf[(size_t)w * 256 + t] = upd[(size_t)(w * 3 + 2) * 256 + t] + a0 * q0 + a1 * q1;
}

// write cat_feat into xz cols 128..139, zero 140..143
__global__ __launch_bounds__(NTH) void k_cat(const float* __restrict__ cat_feat,
                                             float* __restrict__ xz, int nw, int win0) {
    int i = blockIdx.x * NTH + threadIdx.x;
    if (i >= nw * 16) return;
    int w = i >> 4, j = i & 15;
    xz[(size_t)w * 144 + 128 + j] = (j < 12) ? cat_feat[(size_t)(win0 + w) * 12 + j] : 0.f;
}

// final dot: out[w] = z2[w] . f_W3 + b3
__global__ __launch_bounds__(NTH) void k_final(const float* __restrict__ z2,
                                               const float* __restrict__ W3,
                                               const float* __restrict__ b3,
                                               float* __restrict__ out, int nw, int win0) {
    int wv = threadIdx.x >> 6, lane = threadIdx.x & 63;
    int w = blockIdx.x * 4 + wv;
    if (w >= nw) return;
    float s = z2[(size_t)w * 128 + lane] * W3[lane] + z2[(size_t)w * 128 + 64 + lane] * W3[64 + lane];
    for (int off = 32; off; off >>= 1) s += __shfl_xor(s, off);
    if (lane == 0) out[win0 + w] = s + b3[0];
}

extern "C" void kernel_launch(void* const* d_in, const int* in_sizes, int n_in,
                              void* d_out, int out_size, void* d_ws, size_t ws_size,
                              hipStream_t stream) {
    const float* node_table    = (const float*)d_in[0];
    const float* edge_table    = (const float*)d_in[1];
    const float* basis_freq    = (const float*)d_in[2];
    const float* phase         = (const float*)d_in[3];
    const float* ev_W          = (const float*)d_in[4];
    const float* ev_b          = (const float*)d_in[5];
    const float* ev_m1W        = (const float*)d_in[6];
    const float* ev_m1b        = (const float*)d_in[7];
    const float* ev_m2W        = (const float*)d_in[8];
    const float* ev_m2b        = (const float*)d_in[9];
    const float* at_W1         = (const float*)d_in[10];
    const float* at_b1         = (const float*)d_in[11];
    const float* at_W2         = (const float*)d_in[12];
    const float* at_b2         = (const float*)d_in[13];
    const float* at_m1W        = (const float*)d_in[14];
    const float* at_m1b        = (const float*)d_in[15];
    const float* at_m2W        = (const float*)d_in[16];
    const float* at_m2b        = (const float*)d_in[17];
    const float* f_W1          = (const float*)d_in[18];
    const float* f_b1          = (const float*)d_in[19];
    const float* f_W2          = (const float*)d_in[20];
    const float* f_b2          = (const float*)d_in[21];
    const float* f_W3          = (const float*)d_in[22];
    const float* f_b3          = (const float*)d_in[23];
    const float* time_idx      = (const float*)d_in[24];
    const float* cut_time_l    = (const float*)d_in[25];
    const float* cat_feat      = (const float*)d_in[26];
    const float* edge_identify = (const float*)d_in[27];
    const int*   node_idx      = (const int*)d_in[28];
    const int*   edge_idx      = (const int*)d_in[29];

    char* wsb = (char*)d_ws;
    double* acc = (double*)wsb;

    size_t avail = ws_size > 256 ? ws_size - 256 : 0;
    size_t nwc_s = avail / PW_BYTES;
    int nwc = (int)(nwc_s > NWIN_TOTAL ? NWIN_TOTAL : nwc_s);
    if (nwc < 1) nwc = 1;

    float* base = (float*)(wsb + 256);
    // region pointers (aliased by stage lifetime)
    float* evt  = base;                               // [nwc*3][348]
    float* h1   = base;                               // [nwc*3][128]
    float* wp   = base;                               // [nwc][256]
    float* wq   = base + (size_t)nwc * 256;           // [nwc*2][256]
    float* ev   = base + (size_t)nwc * 1044;          // [nwc*3][172]
    float* outf = ev;                                 // [nwc][256]
    float* h2   = ev + (size_t)nwc * 256;             // [nwc][128]
    float* upd  = ev + (size_t)nwc * 516;             // [nwc*3][256]
    float* xz   = upd;                                // [nwc][144]
    float* z1   = upd + (size_t)nwc * 144;            // [nwc][144]
    float* z2   = upd + (size_t)nwc * 288;            // [nwc][128]

    hipMemsetAsync(d_ws, 0, 16, stream);
    k_std<<<64, NTH, 0, stream>>>(time_idx, cut_time_l, acc);

    for (int c0 = 0; c0 < NWIN_TOTAL; c0 += nwc) {
        int nw = NWIN_TOTAL - c0 < nwc ? NWIN_TOTAL - c0 : nwc;
        int M3 = nw * 3;

        k_evt<<<CDIV(M3, 8), NTH, 0, stream>>>(edge_table, basis_freq, phase, time_idx,
                                               cut_time_l, edge_identify, edge_idx, evt, M3, c0);
        k_gemm<348, 347, 172, 6, 1, 0><<<CDIV(M3, 32), NTH, 0, stream>>>(
            evt, ev_W, ev_b, ev, M3, 172, 0, 0);
        for (int dir = 0; dir < 2; ++dir) {
            k_gemm_am<<<CDIV(M3, 32), NTH, 0, stream>>>(
                ev, node_table, node_idx, ev_m1W, ev_m1b, h1, M3, c0, dir);
            k_gemm<128, 128, 128, 4, 0, 0><<<CDIV(M3, 32), NTH, 0, stream>>>(
                h1, ev_m2W, ev_m2b, upd, M3, 256, dir * 128, 0);
        }
        k_gemm<256, 256, 256, 8, 0, 0><<<CDIV(nw, 32), NTH, 0, stream>>>(
            upd, at_W1, at_b1, wp, nw, 256, 0, 1);
        k_gemm<256, 256, 256, 8, 0, 0><<<CDIV(2 * nw, 32), NTH, 0, stream>>>(
            upd, at_W2, at_b2, wq, 2 * nw, 256, 0, 2);
        k_comb<<<nw, NTH, 0, stream>>>(wp, wq, upd, time_idx, cut_time_l, acc, outf, c0);
        k_gemm<256, 256, 128, 4, 0, 1><<<CDIV(nw, 32), NTH, 0, stream>>>(
            outf, at_m1W, at_m1b, h2, nw, 128, 0, 0);
        k_gemm<128, 128, 128, 4, 0, 0><<<CDIV(nw, 32), NTH, 0, stream>>>(
            h2, at_m2W, at_m2b, xz, nw, 144, 0, 0);
        k_cat<<<CDIV(nw * 16, NTH), NTH, 0, stream>>>(cat_feat, xz, nw, c0);
        k_gemm<144, 140, 140, 5, 0, 1><<<CDIV(nw, 32), NTH, 0, stream>>>(
            xz, f_W1, f_b1, z1, nw, 144, 0, 0);
        k_gemm<144, 140, 128, 4, 0, 1><<<CDIV(nw, 32), NTH, 0, stream>>>(
            z1, f_W2, f_b2, z2, nw, 128, 0, 0);
        k_final<<<CDIV(nw, 4), NTH, 0, stream>>>(z2, f_W3, f_b3, (float*)d_out, nw, c0);
    }
}

// Round 5
// 574.809 us; speedup vs baseline: 4.6667x; 2.0092x over previous
//
#include <hip/hip_runtime.h>
#include <math.h>

#define NWIN_TOTAL (256 * 128)
#define NTH 256
#define CDIV(a, b) (((a) + (b) - 1) / (b))

typedef _Float16 f16x8 __attribute__((ext_vector_type(8)));
typedef float f32x4 __attribute__((ext_vector_type(4)));

// ---------------- global std ----------------
__global__ __launch_bounds__(NTH) void k_std(const float* __restrict__ time_idx,
                                             const float* __restrict__ cut,
                                             double* __restrict__ acc) {
    int tid = threadIdx.x;
    const int n = NWIN_TOTAL * 2;
    double s = 0.0, s2 = 0.0;
    for (int i = blockIdx.x * blockDim.x + tid; i < n; i += gridDim.x * blockDim.x) {
        int j = i & 1;
        int bw = i >> 1;
        float d = fabsf(cut[bw >> 7] - time_idx[bw * 3 + j]);
        s += (double)d;
        s2 += (double)d * (double)d;
    }
    __shared__ double ls[NTH], ls2[NTH];
    ls[tid] = s; ls2[tid] = s2;
    __syncthreads();
    for (int st = NTH / 2; st > 0; st >>= 1) {
        if (tid < st) { ls[tid] += ls[tid + st]; ls2[tid] += ls2[tid + st]; }
        __syncthreads();
    }
    if (tid == 0) { atomicAdd(&acc[0], ls[0]); atomicAdd(&acc[1], ls2[0]); }
}

// ---------------- weight -> B-fragment hi/lo planes (fp16 split) ----------------
// frag layout: elem at ((cg*nks + ks)*64 + lane)*8 + j  ==  W[k][col],
// col = cg*16 + (lane&15), k = ks*32 + (lane>>4)*8 + j
__global__ __launch_bounds__(NTH) void k_wprep(const float* __restrict__ src,
                                               int Kt, int Nt, int Kp, int Np,
                                               _Float16* __restrict__ dH,
                                               _Float16* __restrict__ dL) {
    int total = (Np / 16) * (Kp / 32) * 64;
    int idx = blockIdx.x * NTH + threadIdx.x;
    if (idx >= total) return;
    int nks = Kp / 32;
    int cg = idx / (nks * 64);
    int rem = idx - cg * nks * 64;
    int ks = rem >> 6, lane = rem & 63;
    int col = cg * 16 + (lane & 15);
    for (int j = 0; j < 8; ++j) {
        int k = ks * 32 + ((lane >> 4) << 3) + j;
        float v = (k < Kt && col < Nt) ? src[(size_t)k * Nt + col] : 0.f;
        _Float16 h = (_Float16)v;
        float r = v - (float)h;
        dH[(size_t)idx * 8 + j] = h;
        dL[(size_t)idx * 8 + j] = (_Float16)r;
    }
}

// ---------------- generic fp16x3 MFMA GEMM ----------------
#define P_ROWS 0
#define P_EVT  1
#define P_AM   2

struct GP {
    const float* A; int astride; int M;
    const _Float16* Wh; const _Float16* Wl; const float* bias; int ntrue;
    float* C; int ostride; int ocol0;
    // prologue extras
    const float* node_table; const int* node_idx; int dir; int win0;
    const float* edge_table; const float* basis_freq; const float* phase;
    const float* time_idx; const float* cut; const int* edge_idx; const float* eid;
};

template <int PRO, int KPAD, int NPAD, int RELU, int REMAP>
__global__ __launch_bounds__(NTH) void k_gemm(GP p) {
    static_assert(KPAD % 64 == 0, "KPAD must be a multiple of 64");
    constexpr int NKS = KPAD / 32;
    constexpr int NCHUNK = KPAD / 64;
    constexpr int NREP = NPAD / 64;   // colgroups per wave (4 waves)
    __shared__ _Float16 AH[4096];  // [ks2(2)][rg(4)][lane(64)][8]
    __shared__ _Float16 AL[4096];

    const int tid = threadIdx.x;
    const int wv = tid >> 6, lane = tid & 63;
    const int mtile = blockIdx.x * 64;

    f32x4 acc[4][NREP];
#pragma unroll
    for (int rg = 0; rg < 4; ++rg)
#pragma unroll
        for (int j = 0; j < NREP; ++j)
#pragma unroll
            for (int i = 0; i < 4; ++i) acc[rg][j][i] = 0.f;

    for (int kc = 0; kc < NCHUNK; ++kc) {
        __syncthreads();
        // ---- stage A chunk (64 rows x 64 k) as hi/lo frags ----
        for (int s = tid; s < 512; s += NTH) {
            int r = s >> 3, o = s & 7;
            int k0 = kc * 64 + o * 8;
            float v[8];
            int grow = mtile + r;
            if (grow >= p.M) grow = p.M - 1;
            if constexpr (PRO == P_ROWS) {
                int arow = (REMAP == 0) ? grow
                         : (REMAP == 1) ? (grow * 3 + 2)
                                        : ((grow >> 1) * 3 + (grow & 1));
                const float* Ar = p.A + (size_t)arow * p.astride + k0;
                float4 x = *(const float4*)Ar;
                float4 y = *(const float4*)(Ar + 4);
                v[0]=x.x; v[1]=x.y; v[2]=x.z; v[3]=x.w;
                v[4]=y.x; v[5]=y.y; v[6]=y.z; v[7]=y.w;
            } else if constexpr (PRO == P_EVT) {
                int w3 = grow / 3, l = grow - w3 * 3;
                int gw = p.win0 + w3;
                int eidx = p.edge_idx[gw * 3 + l];
                const float* er = p.edge_table + (size_t)eidx * 172;
                float delta = p.cut[gw >> 7] - p.time_idx[gw * 3 + l];
                if (k0 + 7 < 172) {
                    float4 x = *(const float4*)&er[k0];
                    float4 y = *(const float4*)&er[k0 + 4];
                    v[0]=x.x; v[1]=x.y; v[2]=x.z; v[3]=x.w;
                    v[4]=y.x; v[5]=y.y; v[6]=y.z; v[7]=y.w;
                } else if (k0 >= 176 && k0 + 7 < 347) {
#pragma unroll
                    for (int e = 0; e < 8; ++e) {
                        int q = k0 + e - 175;
                        v[e] = cosf(fmaf(delta, p.basis_freq[q], p.phase[q]));
                    }
                } else {
#pragma unroll
                    for (int e = 0; e < 8; ++e) {
                        int k = k0 + e;
                        if (k < 172)      v[e] = er[k];
                        else if (k < 175) v[e] = p.eid[(gw * 3 + l) * 3 + k - 172];
                        else if (k < 347) v[e] = cosf(fmaf(delta, p.basis_freq[k - 175], p.phase[k - 175]));
                        else              v[e] = 0.f;
                    }
                }
            } else {  // P_AM
                int w3 = grow / 3, l = grow - w3 * 3;
                int gw = p.win0 + w3;
                int nb = gw * 6 + 2 * l;
                int si = p.node_idx[nb + p.dir];
                int ti = p.node_idx[nb + 1 - p.dir];
                const float* S = p.node_table + (size_t)si * 172;
                const float* T = p.node_table + (size_t)ti * 172;
                const float* EV = p.A + (size_t)grow * p.astride + k0;
                if (k0 + 7 < 172) {
                    float4 sx = *(const float4*)&S[k0]; float4 sy = *(const float4*)&S[k0 + 4];
                    float4 tx = *(const float4*)&T[k0]; float4 ty = *(const float4*)&T[k0 + 4];
                    float4 ex = *(const float4*)&EV[0]; float4 ey = *(const float4*)&EV[4];
                    v[0] = sx.x + fmaxf(tx.x + ex.x, 0.f);
                    v[1] = sx.y + fmaxf(tx.y + ex.y, 0.f);
                    v[2] = sx.z + fmaxf(tx.z + ex.z, 0.f);
                    v[3] = sx.w + fmaxf(tx.w + ex.w, 0.f);
                    v[4] = sy.x + fmaxf(ty.x + ey.x, 0.f);
                    v[5] = sy.y + fmaxf(ty.y + ey.y, 0.f);
                    v[6] = sy.z + fmaxf(ty.z + ey.z, 0.f);
                    v[7] = sy.w + fmaxf(ty.w + ey.w, 0.f);
                } else {
#pragma unroll
                    for (int e = 0; e < 8; ++e) {
                        int k = k0 + e;
                        v[e] = (k < 172) ? (S[k] + fmaxf(T[k] + EV[e], 0.f)) : 0.f;
                    }
                }
            }
            int ks2 = o >> 2, rg = r >> 4;
            int fl = (r & 15) | ((o & 3) << 4);
            int off = (((ks2 << 2) + rg) * 64 + fl) * 8;
            f16x8 h8, l8;
#pragma unroll
            for (int e = 0; e < 8; ++e) {
                _Float16 h = (_Float16)v[e];
                h8[e] = h;
                l8[e] = (_Float16)(v[e] - (float)h);
            }
            *(f16x8*)&AH[off] = h8;
            *(f16x8*)&AL[off] = l8;
        }
        __syncthreads();
        // ---- compute 2 k-steps ----
#pragma unroll
        for (int k2 = 0; k2 < 2; ++k2) {
            const int ks = kc * 2 + k2;
            f16x8 ah[4], al[4];
#pragma unroll
            for (int rg = 0; rg < 4; ++rg) {
                int off = (((k2 << 2) + rg) * 64 + lane) * 8;
                ah[rg] = *(const f16x8*)&AH[off];
                al[rg] = *(const f16x8*)&AL[off];
            }
#pragma unroll
            for (int j = 0; j < NREP; ++j) {
                int cg = wv * NREP + j;
                size_t boff = ((size_t)(cg * NKS + ks) * 64 + lane) * 8;
                f16x8 bh = *(const f16x8*)&p.Wh[boff];
                f16x8 bl = *(const f16x8*)&p.Wl[boff];
#pragma unroll
                for (int rg = 0; rg < 4; ++rg) {
                    acc[rg][j] = __builtin_amdgcn_mfma_f32_16x16x32_f16(al[rg], bh, acc[rg][j], 0, 0, 0);
                    acc[rg][j] = __builtin_amdgcn_mfma_f32_16x16x32_f16(ah[rg], bl, acc[rg][j], 0, 0, 0);
                    acc[rg][j] = __builtin_amdgcn_mfma_f32_16x16x32_f16(ah[rg], bh, acc[rg][j], 0, 0, 0);
                }
            }
        }
    }
    // ---- epilogue: C layout col=lane&15, row=(lane>>4)*4+i ----
#pragma unroll
    for (int j = 0; j < NREP; ++j) {
        int col = (wv * NREP + j) * 16 + (lane & 15);
        float b = (col < p.ntrue) ? p.bias[col] : 0.f;
#pragma unroll
        for (int rg = 0; rg < 4; ++rg) {
#pragma unroll
            for (int i = 0; i < 4; ++i) {
                int row = mtile + rg * 16 + ((lane >> 4) << 2) + i;
                if (row < p.M) {
                    float v = acc[rg][j][i] + b;
                    if (RELU) v = v > 0.f ? v : 0.f;
                    p.C[(size_t)row * p.ostride + p.ocol0 + col] = v;
                }
            }
        }
    }
}

// ---------------- attention combine ----------------
__global__ __launch_bounds__(NTH) void k_comb(const float* __restrict__ wp,
                                              const float* __restrict__ wq,
                                              const float* __restrict__ upd,
                                              const float* __restrict__ time_idx,
                                              const float* __restrict__ cut,
                                              const double* __restrict__ acc,
                                              float* __restrict__ outf, int win0) {
    const int w = blockIdx.x, t = threadIdx.x;
    const int gw = win0 + w;
    __shared__ float red[NTH];
    __shared__ float sc[2];
    float wpv = wp[(size_t)w * 256 + t];
    float q0 = wq[(size_t)(w * 2 + 0) * 256 + t];
    float q1 = wq[(size_t)(w * 2 + 1) * 256 + t];
    red[t] = wpv * q0;
    __syncthreads();
    for (int st = NTH / 2; st > 0; st >>= 1) { if (t < st) red[t] += red[t + st]; __syncthreads(); }
    if (t == 0) sc[0] = red[0];
    __syncthreads();
    red[t] = wpv * q1;
    __syncthreads();
    for (int st = NTH / 2; st > 0; st >>= 1) { if (t < st) red[t] += red[t + st]; __syncthreads(); }
    if (t == 0) sc[1] = red[0];
    __syncthreads();

    const double n = (double)(NWIN_TOTAL * 2);
    float stdv = (float)sqrt((acc[1] - acc[0] * acc[0] / n) / (n - 1.0));
    float cutv = cut[gw >> 7];
    float d0 = fabsf(cutv - time_idx[gw * 3 + 0]);
    float d1 = fabsf(cutv - time_idx[gw * 3 + 1]);
    float tw0 = expf(-d0 / (stdv + 1e-6f));
    float tw1 = expf(-d1 / (stdv + 1e-6f));
    float s0 = sc[0] * (0.7f + 0.3f * tw0);
    float s1 = sc[1] * (0.7f + 0.3f * tw1);
    float m = fmaxf(s0, s1);
    float e0 = expf(s0 - m), e1 = expf(s1 - m);
    float inv = 1.f / (e0 + e1);
    float a0 = e0 * inv, a1 = e1 * inv;
    outf[(size_t)w * 256 + t] = upd[(size_t)(w * 3 + 2) * 256 + t] + a0 * q0 + a1 * q1;
}

// xz cols 128..191: cat_feat then zeros
__global__ __launch_bounds__(NTH) void k_cat(const float* __restrict__ cat_feat,
                                             float* __restrict__ xz, int nw, int win0) {
    int i = blockIdx.x * NTH + threadIdx.x;
    if (i >= nw * 64) return;
    int w = i >> 6, j = i & 63;
    xz[(size_t)w * 192 + 128 + j] = (j < 12) ? cat_feat[(size_t)(win0 + w) * 12 + j] : 0.f;
}

__global__ __launch_bounds__(NTH) void k_final(const float* __restrict__ z2,
                                               const float* __restrict__ W3,
                                               const float* __restrict__ b3,
                                               float* __restrict__ out, int nw, int win0) {
    int wv = threadIdx.x >> 6, lane = threadIdx.x & 63;
    int w = blockIdx.x * 4 + wv;
    if (w >= nw) return;
    float s = z2[(size_t)w * 128 + lane] * W3[lane] + z2[(size_t)w * 128 + 64 + lane] * W3[64 + lane];
    for (int off = 32; off; off >>= 1) s += __shfl_xor(s, off);
    if (lane == 0) out[win0 + w] = s + b3[0];
}

extern "C" void kernel_launch(void* const* d_in, const int* in_sizes, int n_in,
                              void* d_out, int out_size, void* d_ws, size_t ws_size,
                              hipStream_t stream) {
    const float* node_table    = (const float*)d_in[0];
    const float* edge_table    = (const float*)d_in[1];
    const float* basis_freq    = (const float*)d_in[2];
    const float* phase         = (const float*)d_in[3];
    const float* ev_W          = (const float*)d_in[4];
    const float* ev_b          = (const float*)d_in[5];
    const float* ev_m1W        = (const float*)d_in[6];
    const float* ev_m1b        = (const float*)d_in[7];
    const float* ev_m2W        = (const float*)d_in[8];
    const float* ev_m2b        = (const float*)d_in[9];
    const float* at_W1         = (const float*)d_in[10];
    const float* at_b1         = (const float*)d_in[11];
    const float* at_W2         = (const float*)d_in[12];
    const float* at_b2         = (const float*)d_in[13];
    const float* at_m1W        = (const float*)d_in[14];
    const float* at_m1b        = (const float*)d_in[15];
    const float* at_m2W        = (const float*)d_in[16];
    const float* at_m2b        = (const float*)d_in[17];
    const float* f_W1          = (const float*)d_in[18];
    const float* f_b1          = (const float*)d_in[19];
    const float* f_W2          = (const float*)d_in[20];
    const float* f_b2          = (const float*)d_in[21];
    const float* f_W3          = (const float*)d_in[22];
    const float* f_b3          = (const float*)d_in[23];
    const float* time_idx      = (const float*)d_in[24];
    const float* cut_time_l    = (const float*)d_in[25];
    const float* cat_feat      = (const float*)d_in[26];
    const float* edge_identify = (const float*)d_in[27];
    const int*   node_idx      = (const int*)d_in[28];
    const int*   edge_idx      = (const int*)d_in[29];

    char* wsb = (char*)d_ws;
    double* acc = (double*)wsb;

    // ---- weight frag planes (KPAD must be multiple of 64) ----
    const int   wkp[9] = {384, 192, 128, 256, 256, 256, 128, 192, 192};
    const int   wnp[9] = {192, 128, 128, 256, 256, 128, 128, 192, 128};
    const int   wkt[9] = {347, 172, 128, 256, 256, 256, 128, 140, 140};
    const int   wnt[9] = {172, 128, 128, 256, 256, 128, 128, 140, 128};
    const float* wsrc[9] = {ev_W, ev_m1W, ev_m2W, at_W1, at_W2, at_m1W, at_m2W, f_W1, f_W2};
    _Float16* wH[9]; _Float16* wL[9];
    size_t woff = 256;  // bytes
    for (int i = 0; i < 9; ++i) {
        size_t plane = (size_t)wkp[i] * wnp[i];  // elements
        wH[i] = (_Float16*)(wsb + woff);
        wL[i] = wH[i] + plane;
        woff += plane * 2 * sizeof(_Float16);
        woff = (woff + 15) & ~(size_t)15;
    }

    hipMemsetAsync(d_ws, 0, 16, stream);
    k_std<<<64, NTH, 0, stream>>>(time_idx, cut_time_l, acc);
    for (int i = 0; i < 9; ++i) {
        int total = (wnp[i] / 16) * (wkp[i] / 32) * 64;
        k_wprep<<<CDIV(total, NTH), NTH, 0, stream>>>(wsrc[i], wkt[i], wnt[i], wkp[i], wnp[i], wH[i], wL[i]);
    }

    // ---- dynamic region (per-window 2240 floats) ----
    size_t avail = ws_size > woff + 4096 ? ws_size - woff - 4096 : 0;
    size_t nwc_s = avail / (2240 * sizeof(float));
    int nwc = (int)(nwc_s > NWIN_TOTAL ? NWIN_TOTAL : nwc_s);
    if (nwc < 1) nwc = 1;
    float* base = (float*)(wsb + ((woff + 255) & ~(size_t)255));
    float* evB  = base;                         // nwc*576  (ev; later outf/h2/xz/z1/z2)
    float* h1B  = base + (size_t)nwc * 576;     // nwc*384  (h1; later wp)
    float* updB = h1B + (size_t)nwc * 384;      // nwc*768
    float* wqB  = updB + (size_t)nwc * 768;     // nwc*512
    float* outfB = evB;
    float* h2B   = evB + (size_t)nwc * 256;
    float* xzB   = evB + (size_t)nwc * 384;
    float* z1B   = evB;
    float* z2B   = evB + (size_t)nwc * 256;
    float* wpB   = h1B;

    GP q = {};
    q.node_table = node_table; q.node_idx = node_idx;
    q.edge_table = edge_table; q.basis_freq = basis_freq; q.phase = phase;
    q.time_idx = time_idx; q.cut = cut_time_l; q.edge_idx = edge_idx; q.eid = edge_identify;

    for (int c0 = 0; c0 < NWIN_TOTAL; c0 += nwc) {
        int nw = NWIN_TOTAL - c0 < nwc ? NWIN_TOTAL - c0 : nwc;
        int M3 = nw * 3;
        q.win0 = c0;

        // G1: evt @ ev_W -> ev [M3][192]
        q.A = nullptr; q.astride = 0; q.M = M3;
        q.Wh = wH[0]; q.Wl = wL[0]; q.bias = ev_b; q.ntrue = 172;
        q.C = evB; q.ostride = 192; q.ocol0 = 0;
        k_gemm<P_EVT, 384, 192, 0, 0><<<CDIV(M3, 64), NTH, 0, stream>>>(q);

        for (int dir = 0; dir < 2; ++dir) {
            // G2: am @ ev_m1W -> h1 [M3][128] (relu)
            q.A = evB; q.astride = 192; q.M = M3; q.dir = dir;
            q.Wh = wH[1]; q.Wl = wL[1]; q.bias = ev_m1b; q.ntrue = 128;
            q.C = h1B; q.ostride = 128; q.ocol0 = 0;
            k_gemm<P_AM, 192, 128, 1, 0><<<CDIV(M3, 64), NTH, 0, stream>>>(q);
            // G3: h1 @ ev_m2W -> upd [M3][256] cols dir*128
            q.A = h1B; q.astride = 128; q.M = M3;
            q.Wh = wH[2]; q.Wl = wL[2]; q.bias = ev_m2b; q.ntrue = 128;
            q.C = updB; q.ostride = 256; q.ocol0 = dir * 128;
            k_gemm<P_ROWS, 128, 128, 0, 0><<<CDIV(M3, 64), NTH, 0, stream>>>(q);
        }
        // G4: upd[w*3+2] @ at_W1 -> wp [nw][256]
        q.A = updB; q.astride = 256; q.M = nw;
        q.Wh = wH[3]; q.Wl = wL[3]; q.bias = at_b1; q.ntrue = 256;
        q.C = wpB; q.ostride = 256; q.ocol0 = 0;
        k_gemm<P_ROWS, 256, 256, 0, 1><<<CDIV(nw, 64), NTH, 0, stream>>>(q);
        // G5: upd[(g>>1)*3+(g&1)] @ at_W2 -> wq [2nw][256]
        q.A = updB; q.astride = 256; q.M = 2 * nw;
        q.Wh = wH[4]; q.Wl = wL[4]; q.bias = at_b2; q.ntrue = 256;
        q.C = wqB; q.ostride = 256; q.ocol0 = 0;
        k_gemm<P_ROWS, 256, 256, 0, 2><<<CDIV(2 * nw, 64), NTH, 0, stream>>>(q);

        k_comb<<<nw, NTH, 0, stream>>>(wpB, wqB, updB, time_idx, cut_time_l, acc, outfB, c0);

        // G6: outf @ at_m1W -> h2 [nw][128] (relu)
        q.A = outfB; q.astride = 256; q.M = nw;
        q.Wh = wH[5]; q.Wl = wL[5]; q.bias = at_m1b; q.ntrue = 128;
        q.C = h2B; q.ostride = 128; q.ocol0 = 0;
        k_gemm<P_ROWS, 256, 128, 1, 0><<<CDIV(nw, 64), NTH, 0, stream>>>(q);
        // G7: h2 @ at_m2W -> xz [nw][192] cols 0..127
        q.A = h2B; q.astride = 128; q.M = nw;
        q.Wh = wH[6]; q.Wl = wL[6]; q.bias = at_m2b; q.ntrue = 128;
        q.C = xzB; q.ostride = 192; q.ocol0 = 0;
        k_gemm<P_ROWS, 128, 128, 0, 0><<<CDIV(nw, 64), NTH, 0, stream>>>(q);

        k_cat<<<CDIV(nw * 64, NTH), NTH, 0, stream>>>(cat_feat, xzB, nw, c0);

        // G8: xz @ f_W1 -> z1 [nw][192] (relu)
        q.A = xzB; q.astride = 192; q.M = nw;
        q.Wh = wH[7]; q.Wl = wL[7]; q.bias = f_b1; q.ntrue = 140;
        q.C = z1B; q.ostride = 192; q.ocol0 = 0;
        k_gemm<P_ROWS, 192, 192, 1, 0><<<CDIV(nw, 64), NTH, 0, stream>>>(q);
        // G9: z1 @ f_W2 -> z2 [nw][128] (relu)
        q.A = z1B; q.astride = 192; q.M = nw;
        q.Wh = wH[8]; q.Wl = wL[8]; q.bias = f_b2; q.ntrue = 128;
        q.C = z2B; q.ostride = 128; q.ocol0 = 0;
        k_gemm<P_ROWS, 192, 128, 1, 0><<<CDIV(nw, 64), NTH, 0, stream>>>(q);

        k_final<<<CDIV(nw, 4), NTH, 0, stream>>>(z2B, f_W3, f_b3, (float*)d_out, nw, c0);
    }
}

// Round 6
// 436.645 us; speedup vs baseline: 6.1433x; 1.3164x over previous
//
#include <hip/hip_runtime.h>
#include <math.h>

#define NWIN_TOTAL (256 * 128)
#define NTH 256
#define CDIV(a, b) (((a) + (b) - 1) / (b))

typedef _Float16 f16x8 __attribute__((ext_vector_type(8)));
typedef float f32x4 __attribute__((ext_vector_type(4)));

// ---------------- global std ----------------
__global__ __launch_bounds__(NTH) void k_std(const float* __restrict__ time_idx,
                                             const float* __restrict__ cut,
                                             double* __restrict__ acc) {
    int tid = threadIdx.x;
    const int n = NWIN_TOTAL * 2;
    double s = 0.0, s2 = 0.0;
    for (int i = blockIdx.x * blockDim.x + tid; i < n; i += gridDim.x * blockDim.x) {
        int j = i & 1;
        int bw = i >> 1;
        float d = fabsf(cut[bw >> 7] - time_idx[bw * 3 + j]);
        s += (double)d;
        s2 += (double)d * (double)d;
    }
    __shared__ double ls[NTH], ls2[NTH];
    ls[tid] = s; ls2[tid] = s2;
    __syncthreads();
    for (int st = NTH / 2; st > 0; st >>= 1) {
        if (tid < st) { ls[tid] += ls[tid + st]; ls2[tid] += ls2[tid + st]; }
        __syncthreads();
    }
    if (tid == 0) { atomicAdd(&acc[0], ls[0]); atomicAdd(&acc[1], ls2[0]); }
}

// ---------------- weight -> B-fragment hi/lo planes (fp16 split) ----------------
__global__ __launch_bounds__(NTH) void k_wprep(const float* __restrict__ src,
                                               int Kt, int Nt, int Kp, int Np,
                                               _Float16* __restrict__ dH,
                                               _Float16* __restrict__ dL) {
    int total = (Np / 16) * (Kp / 32) * 64;
    int idx = blockIdx.x * NTH + threadIdx.x;
    if (idx >= total) return;
    int nks = Kp / 32;
    int cg = idx / (nks * 64);
    int rem = idx - cg * nks * 64;
    int ks = rem >> 6, lane = rem & 63;
    int col = cg * 16 + (lane & 15);
    for (int j = 0; j < 8; ++j) {
        int k = ks * 32 + ((lane >> 4) << 3) + j;
        float v = (k < Kt && col < Nt) ? src[(size_t)k * Nt + col] : 0.f;
        _Float16 h = (_Float16)v;
        float r = v - (float)h;
        dH[(size_t)idx * 8 + j] = h;
        dL[(size_t)idx * 8 + j] = (_Float16)r;
    }
}

// ---------------- frag helpers (swizzled: B ^= (B>>4)&7 spreads bank quads) ----------------
template <int RG>
__device__ __forceinline__ void frag_store(_Float16* AH, _Float16* AL, int r, int o,
                                           const float* v) {
    int B = ((o >> 2) * RG + (r >> 4)) * 64 + ((r & 15) | ((o & 3) << 4));
    int off = (B ^ ((B >> 4) & 7)) * 8;
    f16x8 h8, l8;
#pragma unroll
    for (int e = 0; e < 8; ++e) {
        _Float16 h = (_Float16)v[e];
        h8[e] = h;
        l8[e] = (_Float16)(v[e] - (float)h);
    }
    *(f16x8*)&AH[off] = h8;
    *(f16x8*)&AL[off] = l8;
}

template <int RG, int NREP>
__device__ __forceinline__ void mfma_step(const _Float16* AH, const _Float16* AL,
                                          const _Float16* __restrict__ Wh,
                                          const _Float16* __restrict__ Wl,
                                          int nks, int ks, int k2, int wv, int lane,
                                          f32x4 (&acc)[RG][NREP]) {
    f16x8 ah[RG], al[RG];
#pragma unroll
    for (int rg = 0; rg < RG; ++rg) {
        int B = (k2 * RG + rg) * 64 + lane;
        int off = (B ^ ((B >> 4) & 7)) * 8;
        ah[rg] = *(const f16x8*)&AH[off];
        al[rg] = *(const f16x8*)&AL[off];
    }
#pragma unroll
    for (int j = 0; j < NREP; ++j) {
        int cg = wv * NREP + j;
        size_t boff = ((size_t)(cg * nks + ks) * 64 + lane) * 8;
        f16x8 bh = *(const f16x8*)&Wh[boff];
        f16x8 bl = *(const f16x8*)&Wl[boff];
#pragma unroll
        for (int rg = 0; rg < RG; ++rg) {
            acc[rg][j] = __builtin_amdgcn_mfma_f32_16x16x32_f16(al[rg], bh, acc[rg][j], 0, 0, 0);
            acc[rg][j] = __builtin_amdgcn_mfma_f32_16x16x32_f16(ah[rg], bl, acc[rg][j], 0, 0, 0);
            acc[rg][j] = __builtin_amdgcn_mfma_f32_16x16x32_f16(ah[rg], bh, acc[rg][j], 0, 0, 0);
        }
    }
}

// ---------------- G1: evt @ ev_W -> ev  (M3 x 192), K padded 384 ----------------
struct G1P {
    const _Float16* Wh; const _Float16* Wl; const float* bias;
    float* ev; int M; int win0;
    const float* edge_table; const float* basis_freq; const float* phase;
    const float* time_idx; const float* cut; const int* edge_idx; const float* eid;
};

__global__ __launch_bounds__(NTH) void k_g1(G1P p) {
    __shared__ _Float16 AH[4096], AL[4096];
    const int tid = threadIdx.x, wv = tid >> 6, lane = tid & 63;
    const int mtile = blockIdx.x * 64;
    f32x4 acc[4][3];
#pragma unroll
    for (int rg = 0; rg < 4; ++rg)
#pragma unroll
        for (int j = 0; j < 3; ++j)
#pragma unroll
            for (int i = 0; i < 4; ++i) acc[rg][j][i] = 0.f;

    for (int kc = 0; kc < 6; ++kc) {
        __syncthreads();
        for (int it = 0; it < 2; ++it) {
            int s = tid + it * NTH;
            int r = s >> 3, o = s & 7;
            int k0 = kc * 64 + o * 8;
            int grow = mtile + r;
            if (grow >= p.M) grow = p.M - 1;
            int w3 = grow / 3, l = grow - w3 * 3;
            int gw = p.win0 + w3;
            int eidx = p.edge_idx[gw * 3 + l];
            const float* er = p.edge_table + (size_t)eidx * 172;
            float delta = p.cut[gw >> 7] - p.time_idx[gw * 3 + l];
            float v[8];
            if (k0 + 7 < 172) {
                float4 x = *(const float4*)&er[k0];
                float4 y = *(const float4*)&er[k0 + 4];
                v[0]=x.x; v[1]=x.y; v[2]=x.z; v[3]=x.w;
                v[4]=y.x; v[5]=y.y; v[6]=y.z; v[7]=y.w;
            } else if (k0 >= 176 && k0 + 7 < 347) {
#pragma unroll
                for (int e = 0; e < 8; ++e) {
                    int q = k0 + e - 175;
                    v[e] = cosf(fmaf(delta, p.basis_freq[q], p.phase[q]));
                }
            } else {
#pragma unroll
                for (int e = 0; e < 8; ++e) {
                    int k = k0 + e;
                    if (k < 172)      v[e] = er[k];
                    else if (k < 175) v[e] = p.eid[(gw * 3 + l) * 3 + k - 172];
                    else if (k < 347) v[e] = cosf(fmaf(delta, p.basis_freq[k - 175], p.phase[k - 175]));
                    else              v[e] = 0.f;
                }
            }
            frag_store<4>(AH, AL, r, o, v);
        }
        __syncthreads();
#pragma unroll
        for (int k2 = 0; k2 < 2; ++k2)
            mfma_step<4, 3>(AH, AL, p.Wh, p.Wl, 12, kc * 2 + k2, k2, wv, lane, acc);
    }
#pragma unroll
    for (int j = 0; j < 3; ++j) {
        int col = (wv * 3 + j) * 16 + (lane & 15);
        float b = (col < 172) ? p.bias[col] : 0.f;
#pragma unroll
        for (int rg = 0; rg < 4; ++rg)
#pragma unroll
            for (int i = 0; i < 4; ++i) {
                int row = mtile + rg * 16 + ((lane >> 4) << 2) + i;
                if (row < p.M) p.ev[(size_t)row * 192 + col] = acc[rg][j][i] + b;
            }
    }
}

// ---------------- K2: fused conv (both dirs): am -> h1(LDS) -> upd ----------------
struct ConvP {
    const float* ev; const float* node_table; const int* node_idx;
    const _Float16 *W1h, *W1l, *W2h, *W2l; const float *b1, *b2;
    float* upd; int M; int win0;
};

__global__ __launch_bounds__(NTH) void k_conv(ConvP p) {
    __shared__ _Float16 AH[4096], AL[4096];
    __shared__ float h1L[64 * 132];
    const int tid = threadIdx.x, wv = tid >> 6, lane = tid & 63;
    const int mtile = blockIdx.x * 64;

    for (int dir = 0; dir < 2; ++dir) {
        f32x4 acc[4][2];
#pragma unroll
        for (int rg = 0; rg < 4; ++rg)
#pragma unroll
            for (int j = 0; j < 2; ++j)
#pragma unroll
                for (int i = 0; i < 4; ++i) acc[rg][j][i] = 0.f;

        // GEMM1: am(K=192) @ ev_m1W -> h1 (relu)
        for (int kc = 0; kc < 3; ++kc) {
            __syncthreads();
            for (int it = 0; it < 2; ++it) {
                int s = tid + it * NTH;
                int r = s >> 3, o = s & 7;
                int k0 = kc * 64 + o * 8;
                int grow = mtile + r;
                if (grow >= p.M) grow = p.M - 1;
                int w3 = grow / 3, l = grow - w3 * 3;
                int gw = p.win0 + w3;
                int nb = gw * 6 + 2 * l;
                int si = p.node_idx[nb + dir];
                int ti = p.node_idx[nb + 1 - dir];
                const float* S = p.node_table + (size_t)si * 172;
                const float* T = p.node_table + (size_t)ti * 172;
                const float* EV = p.ev + (size_t)grow * 192 + k0;
                float v[8];
                if (k0 + 7 < 172) {
                    float4 sx = *(const float4*)&S[k0]; float4 sy = *(const float4*)&S[k0 + 4];
                    float4 tx = *(const float4*)&T[k0]; float4 ty = *(const float4*)&T[k0 + 4];
                    float4 ex = *(const float4*)&EV[0]; float4 ey = *(const float4*)&EV[4];
                    v[0] = sx.x + fmaxf(tx.x + ex.x, 0.f);
                    v[1] = sx.y + fmaxf(tx.y + ex.y, 0.f);
                    v[2] = sx.z + fmaxf(tx.z + ex.z, 0.f);
                    v[3] = sx.w + fmaxf(tx.w + ex.w, 0.f);
                    v[4] = sy.x + fmaxf(ty.x + ey.x, 0.f);
                    v[5] = sy.y + fmaxf(ty.y + ey.y, 0.f);
                    v[6] = sy.z + fmaxf(ty.z + ey.z, 0.f);
                    v[7] = sy.w + fmaxf(ty.w + ey.w, 0.f);
                } else {
#pragma unroll
                    for (int e = 0; e < 8; ++e) {
                        int k = k0 + e;
                        v[e] = (k < 172) ? (S[k] + fmaxf(T[k] + EV[e], 0.f)) : 0.f;
                    }
                }
                frag_store<4>(AH, AL, r, o, v);
            }
            __syncthreads();
#pragma unroll
            for (int k2 = 0; k2 < 2; ++k2)
                mfma_step<4, 2>(AH, AL, p.W1h, p.W1l, 6, kc * 2 + k2, k2, wv, lane, acc);
        }
        __syncthreads();
#pragma unroll
        for (int j = 0; j < 2; ++j) {
            int col = (wv * 2 + j) * 16 + (lane & 15);
            float b = p.b1[col];
#pragma unroll
            for (int rg = 0; rg < 4; ++rg)
#pragma unroll
                for (int i = 0; i < 4; ++i) {
                    int row = rg * 16 + ((lane >> 4) << 2) + i;
                    float x = acc[rg][j][i] + b;
                    h1L[row * 132 + col] = x > 0.f ? x : 0.f;
                }
        }

        // GEMM2: h1 @ ev_m2W -> upd cols dir*128
        f32x4 acc2[4][2];
#pragma unroll
        for (int rg = 0; rg < 4; ++rg)
#pragma unroll
            for (int j = 0; j < 2; ++j)
#pragma unroll
                for (int i = 0; i < 4; ++i) acc2[rg][j][i] = 0.f;
        for (int kc = 0; kc < 2; ++kc) {
            __syncthreads();
            for (int it = 0; it < 2; ++it) {
                int s = tid + it * NTH;
                int r = s >> 3, o = s & 7;
                int k0 = kc * 64 + o * 8;
                float v[8];
                float4 x = *(const float4*)&h1L[r * 132 + k0];
                float4 y = *(const float4*)&h1L[r * 132 + k0 + 4];
                v[0]=x.x; v[1]=x.y; v[2]=x.z; v[3]=x.w;
                v[4]=y.x; v[5]=y.y; v[6]=y.z; v[7]=y.w;
                frag_store<4>(AH, AL, r, o, v);
            }
            __syncthreads();
#pragma unroll
            for (int k2 = 0; k2 < 2; ++k2)
                mfma_step<4, 2>(AH, AL, p.W2h, p.W2l, 4, kc * 2 + k2, k2, wv, lane, acc2);
        }
#pragma unroll
        for (int j = 0; j < 2; ++j) {
            int col = (wv * 2 + j) * 16 + (lane & 15);
            float b = p.b2[col];
#pragma unroll
            for (int rg = 0; rg < 4; ++rg)
#pragma unroll
                for (int i = 0; i < 4; ++i) {
                    int row = mtile + rg * 16 + ((lane >> 4) << 2) + i;
                    if (row < p.M)
                        p.upd[(size_t)row * 256 + dir * 128 + col] = acc2[rg][j][i] + b;
                }
        }
    }
}

// ---------------- K3: fused attention + head (32 windows / block) ----------------
struct AttnP {
    const float* upd;
    const _Float16 *W1h,*W1l,*W2h,*W2l,*M1h,*M1l,*M2h,*M2l,*F1h,*F1l,*F2h,*F2l;
    const float *ab1,*ab2,*am1b,*am2b,*fb1,*fb2,*fW3,*fb3;
    const float *time_idx,*cut,*cat; const double* acc;
    float* out; int nw; int win0;
};

__global__ __launch_bounds__(NTH) void k_attn(AttnP p) {
    __shared__ float R1[32 * 260];            // wp -> outf -> xz(stride 196)
    __shared__ _Float16 R2h[64 * 264];        // wq fp16 -> h2L f32 [32][132] -> z1L f32 [32][196]
    __shared__ _Float16 AH[2048], AL[2048];
    __shared__ float scoreL[64], aL[64], finL[32];
    float* R2f = (float*)R2h;
    const int tid = threadIdx.x, wv = tid >> 6, lane = tid & 63;
    const int w0 = blockIdx.x * 32;
    if (tid < 64) scoreL[tid] = 0.f;
    if (tid < 32) finL[tid] = 0.f;

    // ---- Phase A: wp = upd[w*3+2] @ at_W1 + ab1  (M=32,K=256,N=256) ----
    {
        f32x4 acc[2][4];
#pragma unroll
        for (int rg = 0; rg < 2; ++rg)
#pragma unroll
            for (int j = 0; j < 4; ++j)
#pragma unroll
                for (int i = 0; i < 4; ++i) acc[rg][j][i] = 0.f;
        for (int kc = 0; kc < 4; ++kc) {
            __syncthreads();
            {
                int r = tid >> 3, o = tid & 7;
                int k0 = kc * 64 + o * 8;
                int lw = w0 + r; if (lw >= p.nw) lw = p.nw - 1;
                const float* Ar = p.upd + ((size_t)lw * 3 + 2) * 256 + k0;
                float v[8];
                float4 x = *(const float4*)Ar; float4 y = *(const float4*)(Ar + 4);
                v[0]=x.x; v[1]=x.y; v[2]=x.z; v[3]=x.w;
                v[4]=y.x; v[5]=y.y; v[6]=y.z; v[7]=y.w;
                frag_store<2>(AH, AL, r, o, v);
            }
            __syncthreads();
#pragma unroll
            for (int k2 = 0; k2 < 2; ++k2)
                mfma_step<2, 4>(AH, AL, p.W1h, p.W1l, 8, kc * 2 + k2, k2, wv, lane, acc);
        }
#pragma unroll
        for (int j = 0; j < 4; ++j) {
            int col = (wv * 4 + j) * 16 + (lane & 15);
            float b = p.ab1[col];
#pragma unroll
            for (int rg = 0; rg < 2; ++rg)
#pragma unroll
                for (int i = 0; i < 4; ++i) {
                    int row = rg * 16 + ((lane >> 4) << 2) + i;
                    R1[row * 260 + col] = acc[rg][j][i] + b;
                }
        }
    }

    // ---- Phase B: wq (two 32-row subtiles) + score partials ----
    for (int st = 0; st < 2; ++st) {
        f32x4 acc[2][4];
#pragma unroll
        for (int rg = 0; rg < 2; ++rg)
#pragma unroll
            for (int j = 0; j < 4; ++j)
#pragma unroll
                for (int i = 0; i < 4; ++i) acc[rg][j][i] = 0.f;
        for (int kc = 0; kc < 4; ++kc) {
            __syncthreads();
            {
                int r = tid >> 3, o = tid & 7;
                int k0 = kc * 64 + o * 8;
                int g = st * 32 + r;
                int lw = w0 + (g >> 1); if (lw >= p.nw) lw = p.nw - 1;
                const float* Ar = p.upd + ((size_t)lw * 3 + (g & 1)) * 256 + k0;
                float v[8];
                float4 x = *(const float4*)Ar; float4 y = *(const float4*)(Ar + 4);
                v[0]=x.x; v[1]=x.y; v[2]=x.z; v[3]=x.w;
                v[4]=y.x; v[5]=y.y; v[6]=y.z; v[7]=y.w;
                frag_store<2>(AH, AL, r, o, v);
            }
            __syncthreads();
#pragma unroll
            for (int k2 = 0; k2 < 2; ++k2)
                mfma_step<2, 4>(AH, AL, p.W2h, p.W2l, 8, kc * 2 + k2, k2, wv, lane, acc);
        }
        float scp[2][4];
#pragma unroll
        for (int rg = 0; rg < 2; ++rg)
#pragma unroll
            for (int i = 0; i < 4; ++i) scp[rg][i] = 0.f;
#pragma unroll
        for (int j = 0; j < 4; ++j) {
            int col = (wv * 4 + j) * 16 + (lane & 15);
            float b = p.ab2[col];
#pragma unroll
            for (int rg = 0; rg < 2; ++rg)
#pragma unroll
                for (int i = 0; i < 4; ++i) {
                    int row = rg * 16 + ((lane >> 4) << 2) + i;
                    int g = st * 32 + row;
                    float v = acc[rg][j][i] + b;
                    R2h[g * 264 + col] = (_Float16)v;
                    scp[rg][i] += v * R1[(g >> 1) * 260 + col];
                }
        }
#pragma unroll
        for (int rg = 0; rg < 2; ++rg)
#pragma unroll
            for (int i = 0; i < 4; ++i) {
                float sv = scp[rg][i];
#pragma unroll
                for (int off = 1; off < 16; off <<= 1) sv += __shfl_xor(sv, off);
                if ((lane & 15) == 0) {
                    int g = st * 32 + rg * 16 + ((lane >> 4) << 2) + i;
                    atomicAdd(&scoreL[g], sv);
                }
            }
    }
    __syncthreads();

    // ---- Phase C: softmax alphas + outf build (into R1) ----
    if (tid < 32) {
        int lw = w0 + tid; if (lw >= p.nw) lw = p.nw - 1;
        int gw = p.win0 + lw;
        const double n = (double)(NWIN_TOTAL * 2);
        float stdv = (float)sqrt((p.acc[1] - p.acc[0] * p.acc[0] / n) / (n - 1.0));
        float cutv = p.cut[gw >> 7];
        float d0 = fabsf(cutv - p.time_idx[gw * 3 + 0]);
        float d1 = fabsf(cutv - p.time_idx[gw * 3 + 1]);
        float tw0 = expf(-d0 / (stdv + 1e-6f));
        float tw1 = expf(-d1 / (stdv + 1e-6f));
        float s0 = scoreL[tid * 2 + 0] * (0.7f + 0.3f * tw0);
        float s1 = scoreL[tid * 2 + 1] * (0.7f + 0.3f * tw1);
        float m = fmaxf(s0, s1);
        float e0 = expf(s0 - m), e1 = expf(s1 - m);
        float inv = 1.f / (e0 + e1);
        aL[tid * 2 + 0] = e0 * inv;
        aL[tid * 2 + 1] = e1 * inv;
    }
    __syncthreads();
    for (int q = tid; q < 32 * 256; q += NTH) {
        int r = q >> 8, c = q & 255;
        int lw = w0 + r; if (lw >= p.nw) lw = p.nw - 1;
        float u2 = p.upd[((size_t)lw * 3 + 2) * 256 + c];
        R1[r * 260 + c] = u2 + aL[r * 2] * (float)R2h[(r * 2) * 264 + c]
                             + aL[r * 2 + 1] * (float)R2h[(r * 2 + 1) * 264 + c];
    }

    // ---- Phase D: h2 = relu(outf @ at_m1W)  K=256 N=128 -> R2f[32][132] ----
    {
        f32x4 acc[2][2];
#pragma unroll
        for (int rg = 0; rg < 2; ++rg)
#pragma unroll
            for (int j = 0; j < 2; ++j)
#pragma unroll
                for (int i = 0; i < 4; ++i) acc[rg][j][i] = 0.f;
        for (int kc = 0; kc < 4; ++kc) {
            __syncthreads();
            {
                int r = tid >> 3, o = tid & 7;
                int k0 = kc * 64 + o * 8;
                float v[8];
                float4 x = *(const float4*)&R1[r * 260 + k0];
                float4 y = *(const float4*)&R1[r * 260 + k0 + 4];
                v[0]=x.x; v[1]=x.y; v[2]=x.z; v[3]=x.w;
                v[4]=y.x; v[5]=y.y; v[6]=y.z; v[7]=y.w;
                frag_store<2>(AH, AL, r, o, v);
            }
            __syncthreads();
#pragma unroll
            for (int k2 = 0; k2 < 2; ++k2)
                mfma_step<2, 2>(AH, AL, p.M1h, p.M1l, 8, kc * 2 + k2, k2, wv, lane, acc);
        }
        __syncthreads();
#pragma unroll
        for (int j = 0; j < 2; ++j) {
            int col = (wv * 2 + j) * 16 + (lane & 15);
            float b = p.am1b[col];
#pragma unroll
            for (int rg = 0; rg < 2; ++rg)
#pragma unroll
                for (int i = 0; i < 4; ++i) {
                    int row = rg * 16 + ((lane >> 4) << 2) + i;
                    float x = acc[rg][j][i] + b;
                    R2f[row * 132 + col] = x > 0.f ? x : 0.f;
                }
        }
    }
    __syncthreads();

    // ---- xz extra cols (cat_feat / zeros) into R1 stride 196 ----
    for (int q = tid; q < 32 * 68; q += NTH) {
        int r = q / 68, c = 128 + q % 68;
        int lw = w0 + r; if (lw >= p.nw) lw = p.nw - 1;
        int gw = p.win0 + lw;
        R1[r * 196 + c] = (c < 140) ? p.cat[(size_t)gw * 12 + (c - 128)] : 0.f;
    }

    // ---- Phase E: h3 = h2 @ at_m2W  K=128 N=128 -> xz cols 0..127 (R1 stride 196) ----
    {
        f32x4 acc[2][2];
#pragma unroll
        for (int rg = 0; rg < 2; ++rg)
#pragma unroll
            for (int j = 0; j < 2; ++j)
#pragma unroll
                for (int i = 0; i < 4; ++i) acc[rg][j][i] = 0.f;
        for (int kc = 0; kc < 2; ++kc) {
            __syncthreads();
            {
                int r = tid >> 3, o = tid & 7;
                int k0 = kc * 64 + o * 8;
                float v[8];
                float4 x = *(const float4*)&R2f[r * 132 + k0];
                float4 y = *(const float4*)&R2f[r * 132 + k0 + 4];
                v[0]=x.x; v[1]=x.y; v[2]=x.z; v[3]=x.w;
                v[4]=y.x; v[5]=y.y; v[6]=y.z; v[7]=y.w;
                frag_store<2>(AH, AL, r, o, v);
            }
            __syncthreads();
#pragma unroll
            for (int k2 = 0; k2 < 2; ++k2)
                mfma_step<2, 2>(AH, AL, p.M2h, p.M2l, 4, kc * 2 + k2, k2, wv, lane, acc);
        }
        __syncthreads();
#pragma unroll
        for (int j = 0; j < 2; ++j) {
            int col = (wv * 2 + j) * 16 + (lane & 15);
            float b = p.am2b[col];
#pragma unroll
            for (int rg = 0; rg < 2; ++rg)
#pragma unroll
                for (int i = 0; i < 4; ++i) {
                    int row = rg * 16 + ((lane >> 4) << 2) + i;
                    R1[row * 196 + col] = acc[rg][j][i] + b;
                }
        }
    }

    // ---- Phase F: z1 = relu(xz @ f_W1)  K=192 N=192 -> z1L (R2f stride 196) ----
    {
        f32x4 acc[2][3];
#pragma unroll
        for (int rg = 0; rg < 2; ++rg)
#pragma unroll
            for (int j = 0; j < 3; ++j)
#pragma unroll
                for (int i = 0; i < 4; ++i) acc[rg][j][i] = 0.f;
        for (int kc = 0; kc < 3; ++kc) {
            __syncthreads();
            {
                int r = tid >> 3, o = tid & 7;
                int k0 = kc * 64 + o * 8;
                float v[8];
                float4 x = *(const float4*)&R1[r * 196 + k0];
                float4 y = *(const float4*)&R1[r * 196 + k0 + 4];
                v[0]=x.x; v[1]=x.y; v[2]=x.z; v[3]=x.w;
                v[4]=y.x; v[5]=y.y; v[6]=y.z; v[7]=y.w;
                frag_store<2>(AH, AL, r, o, v);
            }
            __syncthreads();
#pragma unroll
            for (int k2 = 0; k2 < 2; ++k2)
                mfma_step<2, 3>(AH, AL, p.F1h, p.F1l, 6, kc * 2 + k2, k2, wv, lane, acc);
        }
        __syncthreads();
#pragma unroll
        for (int j = 0; j < 3; ++j) {
            int col = (wv * 3 + j) * 16 + (lane & 15);
            float b = (col < 140) ? p.fb1[col] : 0.f;
#pragma unroll
            for (int rg = 0; rg < 2; ++rg)
#pragma unroll
                for (int i = 0; i < 4; ++i) {
                    int row = rg * 16 + ((lane >> 4) << 2) + i;
                    float x = acc[rg][j][i] + b;
                    R2f[row * 196 + col] = x > 0.f ? x : 0.f;
                }
        }
    }

    // ---- Phase G: z2 = relu(z1 @ f_W2) fused with final dot (f_W3) ----
    {
        f32x4 acc[2][2];
#pragma unroll
        for (int rg = 0; rg < 2; ++rg)
#pragma unroll
            for (int j = 0; j < 2; ++j)
#pragma unroll
                for (int i = 0; i < 4; ++i) acc[rg][j][i] = 0.f;
        for (int kc = 0; kc < 3; ++kc) {
            __syncthreads();
            {
                int r = tid >> 3, o = tid & 7;
                int k0 = kc * 64 + o * 8;
                float v[8];
                float4 x = *(const float4*)&R2f[r * 196 + k0];
                float4 y = *(const float4*)&R2f[r * 196 + k0 + 4];
                v[0]=x.x; v[1]=x.y; v[2]=x.z; v[3]=x.w;
                v[4]=y.x; v[5]=y.y; v[6]=y.z; v[7]=y.w;
                frag_store<2>(AH, AL, r, o, v);
            }
            __syncthreads();
#pragma unroll
            for (int k2 = 0; k2 < 2; ++k2)
                mfma_step<2, 2>(AH, AL, p.F2h, p.F2l, 6, kc * 2 + k2, k2, wv, lane, acc);
        }
        float pt[2][4];
#pragma unroll
        for (int rg = 0; rg < 2; ++rg)
#pragma unroll
            for (int i = 0; i < 4; ++i) pt[rg][i] = 0.f;
#pragma unroll
        for (int j = 0; j < 2; ++j) {
            int col = (wv * 2 + j) * 16 + (lane & 15);
            float b = p.fb2[col];
            float w3 = p.fW3[col];
#pragma unroll
            for (int rg = 0; rg < 2; ++rg)
#pragma unroll
                for (int i = 0; i < 4; ++i) {
                    float x = acc[rg][j][i] + b;
                    x = x > 0.f ? x : 0.f;
                    pt[rg][i] += x * w3;
                }
        }
#pragma unroll
        for (int rg = 0; rg < 2; ++rg)
#pragma unroll
            for (int i = 0; i < 4; ++i) {
                float sv = pt[rg][i];
#pragma unroll
                for (int off = 1; off < 16; off <<= 1) sv += __shfl_xor(sv, off);
                if ((lane & 15) == 0)
                    atomicAdd(&finL[rg * 16 + ((lane >> 4) << 2) + i], sv);
            }
    }
    __syncthreads();
    if (tid < 32 && w0 + tid < p.nw)
        p.out[p.win0 + w0 + tid] = finL[tid] + p.fb3[0];
}

extern "C" void kernel_launch(void* const* d_in, const int* in_sizes, int n_in,
                              void* d_out, int out_size, void* d_ws, size_t ws_size,
                              hipStream_t stream) {
    const float* node_table    = (const float*)d_in[0];
    const float* edge_table    = (const float*)d_in[1];
    const float* basis_freq    = (const float*)d_in[2];
    const float* phase         = (const float*)d_in[3];
    const float* ev_W          = (const float*)d_in[4];
    const float* ev_b          = (const float*)d_in[5];
    const float* ev_m1W        = (const float*)d_in[6];
    const float* ev_m1b        = (const float*)d_in[7];
    const float* ev_m2W        = (const float*)d_in[8];
    const float* ev_m2b        = (const float*)d_in[9];
    const float* at_W1         = (const float*)d_in[10];
    const float* at_b1         = (const float*)d_in[11];
    const float* at_W2         = (const float*)d_in[12];
    const float* at_b2         = (const float*)d_in[13];
    const float* at_m1W        = (const float*)d_in[14];
    const float* at_m1b        = (const float*)d_in[15];
    const float* at_m2W        = (const float*)d_in[16];
    const float* at_m2b        = (const float*)d_in[17];
    const float* f_W1          = (const float*)d_in[18];
    const float* f_b1          = (const float*)d_in[19];
    const float* f_W2          = (const float*)d_in[20];
    const float* f_b2          = (const float*)d_in[21];
    const float* f_W3          = (const float*)d_in[22];
    const float* f_b3          = (const float*)d_in[23];
    const float* time_idx      = (const float*)d_in[24];
    const float* cut_time_l    = (const float*)d_in[25];
    const float* cat_feat      = (const float*)d_in[26];
    const float* edge_identify = (const float*)d_in[27];
    const int*   node_idx      = (const int*)d_in[28];
    const int*   edge_idx      = (const int*)d_in[29];

    char* wsb = (char*)d_ws;
    double* acc = (double*)wsb;

    // ---- weight frag planes ----
    const int   wkp[9] = {384, 192, 128, 256, 256, 256, 128, 192, 192};
    const int   wnp[9] = {192, 128, 128, 256, 256, 128, 128, 192, 128};
    const int   wkt[9] = {347, 172, 128, 256, 256, 256, 128, 140, 140};
    const int   wnt[9] = {172, 128, 128, 256, 256, 128, 128, 140, 128};
    const float* wsrc[9] = {ev_W, ev_m1W, ev_m2W, at_W1, at_W2, at_m1W, at_m2W, f_W1, f_W2};
    _Float16* wH[9]; _Float16* wL[9];
    size_t woff = 256;
    for (int i = 0; i < 9; ++i) {
        size_t plane = (size_t)wkp[i] * wnp[i];
        wH[i] = (_Float16*)(wsb + woff);
        wL[i] = wH[i] + plane;
        woff += plane * 2 * sizeof(_Float16);
        woff = (woff + 15) & ~(size_t)15;
    }

    hipMemsetAsync(d_ws, 0, 16, stream);
    k_std<<<64, NTH, 0, stream>>>(time_idx, cut_time_l, acc);
    for (int i = 0; i < 9; ++i) {
        int total = (wnp[i] / 16) * (wkp[i] / 32) * 64;
        k_wprep<<<CDIV(total, NTH), NTH, 0, stream>>>(wsrc[i], wkt[i], wnt[i], wkp[i], wnp[i], wH[i], wL[i]);
    }

    // ---- dynamic region: per-window = ev 576 + upd 768 = 1344 floats ----
    size_t avail = ws_size > woff + 4096 ? ws_size - woff - 4096 : 0;
    size_t nwc_s = avail / (1344 * sizeof(float));
    int nwc = (int)(nwc_s > NWIN_TOTAL ? NWIN_TOTAL : nwc_s);
    if (nwc < 1) nwc = 1;
    float* base = (float*)(wsb + ((woff + 255) & ~(size_t)255));
    float* evB  = base;                       // [nwc*3][192]
    float* updB = base + (size_t)nwc * 576;   // [nwc*3][256]

    for (int c0 = 0; c0 < NWIN_TOTAL; c0 += nwc) {
        int nw = NWIN_TOTAL - c0 < nwc ? NWIN_TOTAL - c0 : nwc;
        int M3 = nw * 3;

        G1P g = {};
        g.Wh = wH[0]; g.Wl = wL[0]; g.bias = ev_b;
        g.ev = evB; g.M = M3; g.win0 = c0;
        g.edge_table = edge_table; g.basis_freq = basis_freq; g.phase = phase;
        g.time_idx = time_idx; g.cut = cut_time_l; g.edge_idx = edge_idx; g.eid = edge_identify;
        k_g1<<<CDIV(M3, 64), NTH, 0, stream>>>(g);

        ConvP cp = {};
        cp.ev = evB; cp.node_table = node_table; cp.node_idx = node_idx;
        cp.W1h = wH[1]; cp.W1l = wL[1]; cp.W2h = wH[2]; cp.W2l = wL[2];
        cp.b1 = ev_m1b; cp.b2 = ev_m2b;
        cp.upd = updB; cp.M = M3; cp.win0 = c0;
        k_conv<<<CDIV(M3, 64), NTH, 0, stream>>>(cp);

        AttnP ap = {};
        ap.upd = updB;
        ap.W1h = wH[3]; ap.W1l = wL[3]; ap.W2h = wH[4]; ap.W2l = wL[4];
        ap.M1h = wH[5]; ap.M1l = wL[5]; ap.M2h = wH[6]; ap.M2l = wL[6];
        ap.F1h = wH[7]; ap.F1l = wL[7]; ap.F2h = wH[8]; ap.F2l = wL[8];
        ap.ab1 = at_b1; ap.ab2 = at_b2; ap.am1b = at_m1b; ap.am2b = at_m2b;
        ap.fb1 = f_b1; ap.fb2 = f_b2; ap.fW3 = f_W3; ap.fb3 = f_b3;
        ap.time_idx = time_idx; ap.cut = cut_time_l; ap.cat = cat_feat; ap.acc = acc;
        ap.out = (float*)d_out; ap.nw = nw; ap.win0 = c0;
        k_attn<<<CDIV(nw, 32), NTH, 0, stream>>>(ap);
    }
}